// Round 1
// baseline (111.537 us; speedup 1.0000x reference)
//
#include <hip/hip_runtime.h>

#define DD 256
#define NBATCH 8
#define NROW 2048
#define TROWS (NBATCH*NROW)   // 16384 rows per feature tensor

typedef __attribute__((ext_vector_type(8))) short short8;
typedef __attribute__((ext_vector_type(4))) float f32x4;

__device__ __forceinline__ unsigned short f2bf(float f) {
  unsigned int u = __float_as_uint(f);
  u += 0x7FFFu + ((u >> 16) & 1u);   // RNE
  return (unsigned short)(u >> 16);
}
__device__ __forceinline__ float bf2f(unsigned short s) {
  union { unsigned int u; float f; } v; v.u = ((unsigned int)s) << 16; return v.f;
}

__device__ __forceinline__ void gload_lds16(const unsigned short* g, unsigned short* l) {
  __builtin_amdgcn_global_load_lds(
      (const __attribute__((address_space(1))) unsigned int*)(const void*)g,
      (__attribute__((address_space(3))) unsigned int*)(void*)l,
      16, 0, 0);
}

// ---------------- fp32 -> bf16 conversion of features ----------------
__global__ void k_convert(const float* __restrict__ x1, const float* __restrict__ x2,
                          unsigned short* __restrict__ xb)
{
  const long long i = (long long)blockIdx.x * 256 + threadIdx.x;
  const long long base = i * 8;
  const long long n1 = (long long)TROWS * DD; // 4,194,304 floats per tensor
  const float* src = (base < n1) ? (x1 + base) : (x2 + (base - n1));
  float4 a = *(const float4*)(src);
  float4 b = *(const float4*)(src + 4);
  union { unsigned short us[8]; int4 v; } u;
  u.us[0]=f2bf(a.x); u.us[1]=f2bf(a.y); u.us[2]=f2bf(a.z); u.us[3]=f2bf(a.w);
  u.us[4]=f2bf(b.x); u.us[5]=f2bf(b.y); u.us[6]=f2bf(b.z); u.us[7]=f2bf(b.w);
  *(int4*)(xb + base) = u.v;
}

// ---------------- Msym = (M+M^T)/2 ; Wbf = bf16(W) ----------------
__global__ void k_msym(const float* __restrict__ metric, const float* __restrict__ W,
                       float* __restrict__ Msym, unsigned short* __restrict__ Wbf)
{
  int i = blockIdx.x * 256 + threadIdx.x;   // 65536
  int r = i >> 8, c = i & 255;
  Msym[i] = 0.5f * (metric[r*DD + c] + metric[c*DD + r]);
  Wbf[i]  = f2bf(W[i]);
}

// ---------------- WpT = Msym @ W (bf16) ; bp = Msym @ b ----------------
__global__ void k_wpt(const float* __restrict__ Msym, const float* __restrict__ W,
                      const float* __restrict__ bvec,
                      unsigned short* __restrict__ WpT, float* __restrict__ bp)
{
  int e = blockIdx.x, d = threadIdx.x;
  float acc = 0.f;
  for (int j = 0; j < DD; ++j) acc += Msym[e*DD + j] * W[j*DD + d];
  WpT[e*DD + d] = f2bf(acc);
  __shared__ float red[256];
  red[d] = Msym[e*DD + d] * bvec[d];
  __syncthreads();
  for (int s = 128; s; s >>= 1) { if (d < s) red[d] += red[d + s]; __syncthreads(); }
  if (d == 0) bp[e] = red[0];
}

// ---------------- q[n] = sum_d f[n][d]*fM[n][d] ----------------
__global__ void k_q(const unsigned short* __restrict__ f1, const unsigned short* __restrict__ f1M,
                    const unsigned short* __restrict__ f2, const unsigned short* __restrict__ f2M,
                    float* __restrict__ q1, float* __restrict__ q2)
{
  const int wave = threadIdx.x >> 6, lane = threadIdx.x & 63;
  const int row = blockIdx.x * 4 + wave;     // 0..16383
  const unsigned short *pa, *pb; float* qo;
  if (blockIdx.y == 0) { pa = f1; pb = f1M; qo = q1; }
  else                 { pa = f2; pb = f2M; qo = q2; }
  const long long off = (long long)row * DD + lane * 4;
  ushort4 ua = *(const ushort4*)(pa + off);
  ushort4 ub = *(const ushort4*)(pb + off);
  float s = bf2f(ua.x)*bf2f(ub.x) + bf2f(ua.y)*bf2f(ub.y)
          + bf2f(ua.z)*bf2f(ub.z) + bf2f(ua.w)*bf2f(ub.w);
  for (int o = 32; o; o >>= 1) s += __shfl_down(s, o);
  if (lane == 0) qo[row] = s;
}

// ---------------- NT bf16 MFMA GEMM, 128x128 tile, BK=32, K=256 ----------------
// EPI==0: Cb[row][col] = bf16(acc + bias[col])           (f / fM GEMMs)
// EPI==1: Co = exp(clip(-(q1[row]+q2[col]-2*acc),-10,10)) (cross GEMM, batched via z)
template<int EPI>
__global__ __launch_bounds__(256, 2)
void k_gemm(const unsigned short* __restrict__ A,
            const unsigned short* __restrict__ B,
            const float* __restrict__ bias,
            unsigned short* __restrict__ Cb,
            const float* __restrict__ q1g,
            const float* __restrict__ q2g,
            float* __restrict__ Co,
            int ldc, long long sA, long long sB, long long sC, int sQ)
{
  __shared__ __align__(16) unsigned short As[2][128*32];
  __shared__ __align__(16) unsigned short Bs[2][128*32];
  __shared__ float q1s[128];
  __shared__ float q2s[128];

  const int tid  = threadIdx.x;
  const int lane = tid & 63;
  const int wave = tid >> 6;
  const int wr = wave >> 1;
  const int wc = wave & 1;
  const int row0 = blockIdx.y * 128;
  const int col0 = blockIdx.x * 128;
  const int z = blockIdx.z;

  A += (long long)z * sA;
  B += (long long)z * sB;

  if (EPI == 1) {
    if (tid < 128) q1s[tid]       = q1g[z*sQ + row0 + tid];
    else           q2s[tid - 128] = q2g[z*sQ + col0 + (tid - 128)];
  }

  f32x4 acc[4][4];
#pragma unroll
  for (int m = 0; m < 4; ++m)
#pragma unroll
    for (int n = 0; n < 4; ++n) acc[m][n] = (f32x4){0.f, 0.f, 0.f, 0.f};

  const int lrow = lane >> 2;        // row within 16-row staging chunk
  const int lkk  = (lane & 3) * 8;   // k element offset within staging row

  // prologue: stage k-step 0
#pragma unroll
  for (int c = 0; c < 2; ++c) {
    int chunk = wave * 2 + c;
    gload_lds16(A + (long long)(row0 + chunk*16 + lrow)*DD + lkk, &As[0][chunk*512]);
    gload_lds16(B + (long long)(col0 + chunk*16 + lrow)*DD + lkk, &Bs[0][chunk*512]);
  }
  __syncthreads();

  const int lr = lane & 15;
  const int lk = (lane >> 4) * 8;

#pragma unroll
  for (int kt = 0; kt < 8; ++kt) {
    const int cur = kt & 1;
    if (kt < 7) {
      const int k0 = (kt + 1) * 32;
#pragma unroll
      for (int c = 0; c < 2; ++c) {
        int chunk = wave * 2 + c;
        gload_lds16(A + (long long)(row0 + chunk*16 + lrow)*DD + k0 + lkk, &As[cur^1][chunk*512]);
        gload_lds16(B + (long long)(col0 + chunk*16 + lrow)*DD + k0 + lkk, &Bs[cur^1][chunk*512]);
      }
    }
    short8 af[4], bfr[4];
#pragma unroll
    for (int m = 0; m < 4; ++m) af[m]  = *(const short8*)&As[cur][(wr*64 + m*16 + lr)*32 + lk];
#pragma unroll
    for (int n = 0; n < 4; ++n) bfr[n] = *(const short8*)&Bs[cur][(wc*64 + n*16 + lr)*32 + lk];
#pragma unroll
    for (int m = 0; m < 4; ++m)
#pragma unroll
      for (int n = 0; n < 4; ++n)
        acc[m][n] = __builtin_amdgcn_mfma_f32_16x16x32_bf16(af[m], bfr[n], acc[m][n], 0, 0, 0);
    __syncthreads();
  }

  // epilogue — C/D layout (m89-verified): col = lane&15, row = (lane>>4)*4 + reg
#pragma unroll
  for (int m = 0; m < 4; ++m) {
#pragma unroll
    for (int r = 0; r < 4; ++r) {
      const int rowl = wr*64 + m*16 + (lane >> 4)*4 + r;
#pragma unroll
      for (int n = 0; n < 4; ++n) {
        const int coll = wc*64 + n*16 + (lane & 15);
        const float v = acc[m][n][r];
        if (EPI == 0) {
          Cb[(long long)(row0 + rowl)*ldc + (col0 + coll)] = f2bf(v + bias[col0 + coll]);
        } else {
          float dsq = q1s[rowl] + q2s[coll] - 2.0f * v;
          float sc = fminf(fmaxf(-dsq, -10.0f), 10.0f);
          Co[(long long)z*sC + (long long)(row0 + rowl)*ldc + (col0 + coll)] = __expf(sc);
        }
      }
    }
  }
}

extern "C" void kernel_launch(void* const* d_in, const int* in_sizes, int n_in,
                              void* d_out, int out_size, void* d_ws, size_t ws_size,
                              hipStream_t stream) {
  const float* x1     = (const float*)d_in[0];
  const float* x2     = (const float*)d_in[1];
  const float* W      = (const float*)d_in[2];
  const float* bv     = (const float*)d_in[3];
  const float* metric = (const float*)d_in[4];
  float* out = (float*)d_out;

  // workspace layout (all 16B aligned); total ~48.6 MiB
  if (ws_size < 51000000) return;
  unsigned short* p   = (unsigned short*)d_ws;
  unsigned short* x1b = p; p += 4194304;
  unsigned short* x2b = p; p += 4194304;
  unsigned short* f1  = p; p += 4194304;
  unsigned short* f1M = p; p += 4194304;
  unsigned short* f2  = p; p += 4194304;
  unsigned short* f2M = p; p += 4194304;
  unsigned short* Wbf = p; p += 65536;
  unsigned short* WpT = p; p += 65536;
  float* fp   = (float*)p;
  float* Msym = fp; fp += 65536;
  float* q1   = fp; fp += 16384;
  float* q2   = fp; fp += 16384;
  float* bp   = fp; fp += 256;

  // 1) convert features to bf16 (x1b contiguous with x2b)
  k_convert<<<4096, 256, 0, stream>>>(x1, x2, x1b);
  // 2) small matrix prep
  k_msym<<<256, 256, 0, stream>>>(metric, W, Msym, Wbf);
  k_wpt<<<256, 256, 0, stream>>>(Msym, W, bv, WpT, bp);
  // 3) f and fM GEMMs (NT, bias epilogue, bf16 out)
  dim3 gf(2, 128, 1);
  k_gemm<0><<<gf, 256, 0, stream>>>(x1b, Wbf, bv, f1,  nullptr, nullptr, nullptr, DD, 0, 0, 0, 0);
  k_gemm<0><<<gf, 256, 0, stream>>>(x1b, WpT, bp, f1M, nullptr, nullptr, nullptr, DD, 0, 0, 0, 0);
  k_gemm<0><<<gf, 256, 0, stream>>>(x2b, Wbf, bv, f2,  nullptr, nullptr, nullptr, DD, 0, 0, 0, 0);
  k_gemm<0><<<gf, 256, 0, stream>>>(x2b, WpT, bp, f2M, nullptr, nullptr, nullptr, DD, 0, 0, 0, 0);
  // 4) row quadratic forms
  dim3 gq(4096, 2, 1);
  k_q<<<gq, 256, 0, stream>>>(f1, f1M, f2, f2M, q1, q2);
  // 5) batched cross GEMM + fused similarity epilogue
  dim3 gc(16, 16, 8);
  k_gemm<1><<<gc, 256, 0, stream>>>(f1M, f2, nullptr, nullptr, q1, q2, out,
                                    NROW, (long long)NROW*DD, (long long)NROW*DD,
                                    (long long)NROW*NROW, NROW);
}

// Round 2
// 75.861 us; speedup vs baseline: 1.4703x; 1.4703x over previous
//
#include <hip/hip_runtime.h>

#define DD 256
#define NBATCH 8
#define NROW 2048
#define TROWS (NBATCH*NROW)   // 16384 rows per feature tensor

typedef __attribute__((ext_vector_type(8))) short short8;
typedef __attribute__((ext_vector_type(4))) float f32x4;

__device__ __forceinline__ unsigned short f2bf(float f) {
  unsigned int u = __float_as_uint(f);
  u += 0x7FFFu + ((u >> 16) & 1u);   // RNE
  return (unsigned short)(u >> 16);
}

__device__ __forceinline__ void gload_lds16(const unsigned short* g, unsigned short* l) {
  __builtin_amdgcn_global_load_lds(
      (const __attribute__((address_space(1))) unsigned int*)(const void*)g,
      (__attribute__((address_space(3))) unsigned int*)(void*)l,
      16, 0, 0);
}

// ---------------- fp32 -> bf16 conversion of features ----------------
__global__ void k_convert(const float* __restrict__ x1, const float* __restrict__ x2,
                          unsigned short* __restrict__ xb)
{
  const long long i = (long long)blockIdx.x * 256 + threadIdx.x;
  const long long base = i * 8;
  const long long n1 = (long long)TROWS * DD;
  const float* src = (base < n1) ? (x1 + base) : (x2 + (base - n1));
  float4 a = *(const float4*)(src);
  float4 b = *(const float4*)(src + 4);
  union { unsigned short us[8]; int4 v; } u;
  u.us[0]=f2bf(a.x); u.us[1]=f2bf(a.y); u.us[2]=f2bf(a.z); u.us[3]=f2bf(a.w);
  u.us[4]=f2bf(b.x); u.us[5]=f2bf(b.y); u.us[6]=f2bf(b.z); u.us[7]=f2bf(b.w);
  *(int4*)(xb + base) = u.v;
}

// ---------------- prep: Wbf = bf16(W); WpT = Msym@W (bf16); bp = Msym@b ----
// Msym row e computed in LDS, never materialized.
__global__ void k_prep(const float* __restrict__ metric, const float* __restrict__ W,
                       const float* __restrict__ bvec,
                       unsigned short* __restrict__ Wbf, unsigned short* __restrict__ WpT,
                       float* __restrict__ bp)
{
  __shared__ float msrow[DD];
  __shared__ float red[DD];
  const int e = blockIdx.x, d = threadIdx.x;
  msrow[d] = 0.5f * (metric[e*DD + d] + metric[d*DD + e]);
  Wbf[e*DD + d] = f2bf(W[e*DD + d]);
  __syncthreads();
  float acc = 0.f;
  for (int j = 0; j < DD; ++j) acc += msrow[j] * W[j*DD + d];
  WpT[e*DD + d] = f2bf(acc);
  red[d] = msrow[d] * bvec[d];
  __syncthreads();
  for (int s = 128; s; s >>= 1) { if (d < s) red[d] += red[d + s]; __syncthreads(); }
  if (d == 0) bp[e] = red[0];
}

// ---------------- fused dual-B f-GEMM ----------------
// A = x (bf16), B1 = Wbf, B2 = WpT. Computes f = A@B1^T + b and fM = A@B2^T + bp.
// z==0: writes fM (f1M);  z==1: writes f (f2).
// q partials: qp[slice][row] = sum over this block's 64-col slice of f*fM,
// slice = blockIdx.x*2 + wc  (4 slices of 64 cols).
__global__ __launch_bounds__(256, 2)
void k_fgemm(const unsigned short* __restrict__ x1b, const unsigned short* __restrict__ x2b,
             const unsigned short* __restrict__ B1, const unsigned short* __restrict__ B2,
             const float* __restrict__ bb, const float* __restrict__ bpv,
             unsigned short* __restrict__ o1, unsigned short* __restrict__ o2,
             float* __restrict__ qp1, float* __restrict__ qp2)
{
  __shared__ __align__(16) unsigned short As[2][128*32];
  __shared__ __align__(16) unsigned short B1s[2][128*32];
  __shared__ __align__(16) unsigned short B2s[2][128*32];
  __shared__ float bbs[128], bps[128];

  const int tid  = threadIdx.x;
  const int lane = tid & 63;
  const int wave = tid >> 6;
  const int wr = wave >> 1;
  const int wc = wave & 1;
  const int col0 = blockIdx.x * 128;
  const int row0 = blockIdx.y * 128;
  const int z    = blockIdx.z;

  const unsigned short* A = z ? x2b : x1b;
  unsigned short* outp    = z ? o2  : o1;
  float* qp               = z ? qp2 : qp1;

  if (tid < 128) bbs[tid]       = bb[col0 + tid];
  else           bps[tid - 128] = bpv[col0 + (tid - 128)];

  f32x4 accF[4][4], accM[4][4];
#pragma unroll
  for (int m = 0; m < 4; ++m)
#pragma unroll
    for (int n = 0; n < 4; ++n) { accF[m][n] = (f32x4){0,0,0,0}; accM[m][n] = (f32x4){0,0,0,0}; }

  const int lrow = lane >> 2;
  const int lkk  = (lane & 3) * 8;

#define STAGE_F(buf, k0) do { \
  _Pragma("unroll") \
  for (int c = 0; c < 2; ++c) { \
    const int chunk = wave * 2 + c; \
    const long long ra = (long long)(row0 + chunk*16 + lrow)*DD + (k0) + lkk; \
    const int rb = (col0 + chunk*16 + lrow)*DD + (k0) + lkk; \
    gload_lds16(A  + ra, &As[buf][chunk*512]); \
    gload_lds16(B1 + rb, &B1s[buf][chunk*512]); \
    gload_lds16(B2 + rb, &B2s[buf][chunk*512]); \
  } } while (0)

  STAGE_F(0, 0);
  __syncthreads();

  const int lr = lane & 15;
  const int lk = (lane >> 4) * 8;

#pragma unroll
  for (int kt = 0; kt < 8; ++kt) {
    const int cur = kt & 1;
    if (kt < 7) STAGE_F(cur ^ 1, (kt + 1) * 32);
    short8 af[4], b1f[4], b2f[4];
#pragma unroll
    for (int m = 0; m < 4; ++m) af[m]  = *(const short8*)&As[cur][(wr*64 + m*16 + lr)*32 + lk];
#pragma unroll
    for (int n = 0; n < 4; ++n) {
      b1f[n] = *(const short8*)&B1s[cur][(wc*64 + n*16 + lr)*32 + lk];
      b2f[n] = *(const short8*)&B2s[cur][(wc*64 + n*16 + lr)*32 + lk];
    }
#pragma unroll
    for (int m = 0; m < 4; ++m)
#pragma unroll
      for (int n = 0; n < 4; ++n) {
        accF[m][n] = __builtin_amdgcn_mfma_f32_16x16x32_bf16(af[m], b1f[n], accF[m][n], 0, 0, 0);
        accM[m][n] = __builtin_amdgcn_mfma_f32_16x16x32_bf16(af[m], b2f[n], accM[m][n], 0, 0, 0);
      }
    __syncthreads();
  }

  // epilogue: C/D layout col=lane&15, row=(lane>>4)*4+reg
#pragma unroll
  for (int m = 0; m < 4; ++m) {
#pragma unroll
    for (int r = 0; r < 4; ++r) {
      const int rowl = wr*64 + m*16 + (lane >> 4)*4 + r;
      float p = 0.f;
#pragma unroll
      for (int n = 0; n < 4; ++n) {
        const int coll = wc*64 + n*16 + (lane & 15);
        const float fv  = accF[m][n][r] + bbs[coll];
        const float fMv = accM[m][n][r] + bps[coll];
        p += fv * fMv;
        outp[(long long)(row0 + rowl)*DD + (col0 + coll)] = f2bf(z ? fv : fMv);
      }
      p += __shfl_xor(p, 1); p += __shfl_xor(p, 2);
      p += __shfl_xor(p, 4); p += __shfl_xor(p, 8);
      if ((lane & 15) == 0) qp[(blockIdx.x*2 + wc)*TROWS + row0 + rowl] = p;
    }
  }
#undef STAGE_F
}

// ---------------- batched cross GEMM + fused similarity epilogue ----------
// 1D grid, z = bid&7 pins each batch to one XCD (bijective: 2048 % 8 == 0).
__global__ __launch_bounds__(256, 2)
void k_cross(const unsigned short* __restrict__ f1M, const unsigned short* __restrict__ f2,
             const float* __restrict__ qp1, const float* __restrict__ qp2,
             float* __restrict__ out)
{
  __shared__ __align__(16) unsigned short As[2][128*32];
  __shared__ __align__(16) unsigned short Bs[2][128*32];
  __shared__ float q1s[128];
  __shared__ float q2s[128];

  const int tid  = threadIdx.x;
  const int lane = tid & 63;
  const int wave = tid >> 6;
  const int wr = wave >> 1;
  const int wc = wave & 1;

  const int bid = blockIdx.x;
  const int z  = bid & 7;
  const int t  = bid >> 3;
  const int bx = t & 15;
  const int by = t >> 4;
  const int row0 = by * 128;
  const int col0 = bx * 128;

  const unsigned short* A = f1M + (long long)z * NROW * DD;
  const unsigned short* B = f2  + (long long)z * NROW * DD;

  if (tid < 128) {
    const int rg = z*NROW + row0 + tid;
    q1s[tid] = qp1[rg] + qp1[TROWS + rg] + qp1[2*TROWS + rg] + qp1[3*TROWS + rg];
  } else {
    const int cg = z*NROW + col0 + (tid - 128);
    q2s[tid-128] = qp2[cg] + qp2[TROWS + cg] + qp2[2*TROWS + cg] + qp2[3*TROWS + cg];
  }

  f32x4 acc[4][4];
#pragma unroll
  for (int m = 0; m < 4; ++m)
#pragma unroll
    for (int n = 0; n < 4; ++n) acc[m][n] = (f32x4){0,0,0,0};

  const int lrow = lane >> 2;
  const int lkk  = (lane & 3) * 8;

#define STAGE_C(buf, k0) do { \
  _Pragma("unroll") \
  for (int c = 0; c < 2; ++c) { \
    const int chunk = wave * 2 + c; \
    gload_lds16(A + (long long)(row0 + chunk*16 + lrow)*DD + (k0) + lkk, &As[buf][chunk*512]); \
    gload_lds16(B + (long long)(col0 + chunk*16 + lrow)*DD + (k0) + lkk, &Bs[buf][chunk*512]); \
  } } while (0)

  STAGE_C(0, 0);
  __syncthreads();

  const int lr = lane & 15;
  const int lk = (lane >> 4) * 8;

#pragma unroll
  for (int kt = 0; kt < 8; ++kt) {
    const int cur = kt & 1;
    if (kt < 7) STAGE_C(cur ^ 1, (kt + 1) * 32);
    short8 af[4], bfr[4];
#pragma unroll
    for (int m = 0; m < 4; ++m) af[m]  = *(const short8*)&As[cur][(wr*64 + m*16 + lr)*32 + lk];
#pragma unroll
    for (int n = 0; n < 4; ++n) bfr[n] = *(const short8*)&Bs[cur][(wc*64 + n*16 + lr)*32 + lk];
#pragma unroll
    for (int m = 0; m < 4; ++m)
#pragma unroll
      for (int n = 0; n < 4; ++n)
        acc[m][n] = __builtin_amdgcn_mfma_f32_16x16x32_bf16(af[m], bfr[n], acc[m][n], 0, 0, 0);
    __syncthreads();
  }

  float* outz = out + (long long)z * NROW * NROW;
#pragma unroll
  for (int m = 0; m < 4; ++m) {
#pragma unroll
    for (int r = 0; r < 4; ++r) {
      const int rowl = wr*64 + m*16 + (lane >> 4)*4 + r;
#pragma unroll
      for (int n = 0; n < 4; ++n) {
        const int coll = wc*64 + n*16 + (lane & 15);
        const float dsq = q1s[rowl] + q2s[coll] - 2.0f * acc[m][n][r];
        const float sc = fminf(fmaxf(-dsq, -10.0f), 10.0f);
        outz[(long long)(row0 + rowl)*NROW + (col0 + coll)] = __expf(sc);
      }
    }
  }
#undef STAGE_C
}

extern "C" void kernel_launch(void* const* d_in, const int* in_sizes, int n_in,
                              void* d_out, int out_size, void* d_ws, size_t ws_size,
                              hipStream_t stream) {
  const float* x1     = (const float*)d_in[0];
  const float* x2     = (const float*)d_in[1];
  const float* W      = (const float*)d_in[2];
  const float* bv     = (const float*)d_in[3];
  const float* metric = (const float*)d_in[4];
  float* out = (float*)d_out;

  if (ws_size < 36000000) return;
  unsigned short* p   = (unsigned short*)d_ws;
  unsigned short* x1b = p; p += 4194304;
  unsigned short* x2b = p; p += 4194304;
  unsigned short* f1M = p; p += 4194304;
  unsigned short* f2  = p; p += 4194304;
  unsigned short* Wbf = p; p += 65536;
  unsigned short* WpT = p; p += 65536;
  float* fp  = (float*)p;
  float* qp1 = fp; fp += 4*TROWS;
  float* qp2 = fp; fp += 4*TROWS;
  float* bp  = fp; fp += 256;

  // 1) features -> bf16
  k_convert<<<4096, 256, 0, stream>>>(x1, x2, x1b);
  // 2) prep (Wbf, WpT, bp)
  k_prep<<<256, 256, 0, stream>>>(metric, W, bv, Wbf, WpT, bp);
  // 3) fused dual-B GEMM: f1M, f2, q partials
  dim3 gf(2, 128, 2);
  k_fgemm<<<gf, 256, 0, stream>>>(x1b, x2b, Wbf, WpT, bv, bp, f1M, f2, qp1, qp2);
  // 4) cross GEMM + similarity epilogue (XCD-pinned)
  k_cross<<<2048, 256, 0, stream>>>(f1M, f2, qp1, qp2, out);
}

// Round 3
// 71.071 us; speedup vs baseline: 1.5694x; 1.0674x over previous
//
#include <hip/hip_runtime.h>

#define DD 256
#define NROW 2048
#define TROWS 16384   // 8 batches x 2048 rows

typedef __attribute__((ext_vector_type(8))) short short8;
typedef __attribute__((ext_vector_type(4))) float f32x4;

__device__ __forceinline__ unsigned short f2bf(float f) {
  unsigned int u = __float_as_uint(f);
  u += 0x7FFFu + ((u >> 16) & 1u);   // RNE
  return (unsigned short)(u >> 16);
}

__device__ __forceinline__ void gload_lds16(const unsigned short* g, unsigned short* l) {
  __builtin_amdgcn_global_load_lds(
      (const __attribute__((address_space(1))) unsigned int*)(const void*)g,
      (__attribute__((address_space(3))) unsigned int*)(void*)l,
      16, 0, 0);
}

// ---------------- prep: Wbf = bf16(W); WpT = Msym@W (bf16); bp = Msym@b ----
__global__ void k_prep(const float* __restrict__ metric, const float* __restrict__ W,
                       const float* __restrict__ bvec,
                       unsigned short* __restrict__ Wbf, unsigned short* __restrict__ WpT,
                       float* __restrict__ bp)
{
  __shared__ float msrow[DD];
  __shared__ float red[DD];
  const int e = blockIdx.x, d = threadIdx.x;
  msrow[d] = 0.5f * (metric[e*DD + d] + metric[d*DD + e]);
  Wbf[e*DD + d] = f2bf(W[e*DD + d]);
  __syncthreads();
  float acc = 0.f;
  for (int j = 0; j < DD; ++j) acc += msrow[j] * W[j*DD + d];
  WpT[e*DD + d] = f2bf(acc);
  red[d] = msrow[d] * bvec[d];
  __syncthreads();
  for (int s = 128; s; s >>= 1) { if (d < s) red[d] += red[d + s]; __syncthreads(); }
  if (d == 0) bp[e] = red[0];
}

// ---------------- fused convert + dual-B f-GEMM ----------------
// A = x (fp32, converted in-register), B1 = Wbf, B2 = WpT.
// f = A@B1^T + b ; fM = A@B2^T + bp.
// z==0 (tensor1): writes fM -> o1 (f1M). z==1 (tensor2): writes f -> o2 (f2).
// q partials per 64-col wave slice: qp[wc*TROWS + row].
// BM=64, BN=256 (full width -> A panel read exactly once), BK=32, 4 waves.
__global__ __launch_bounds__(256, 2)
void k_fgemm(const float* __restrict__ x1, const float* __restrict__ x2,
             const unsigned short* __restrict__ B1, const unsigned short* __restrict__ B2,
             const float* __restrict__ bb, const float* __restrict__ bpv,
             unsigned short* __restrict__ o1, unsigned short* __restrict__ o2,
             float* __restrict__ qp1, float* __restrict__ qp2)
{
  __shared__ __align__(16) unsigned short As[2][64*32];     //  8 KB
  __shared__ __align__(16) unsigned short B1s[2][256*32];   // 32 KB
  __shared__ __align__(16) unsigned short B2s[2][256*32];   // 32 KB

  const int tid  = threadIdx.x;
  const int lane = tid & 63;
  const int wave = tid >> 6;      // 0..3 = column group (64 cols each)
  const int row0 = blockIdx.x * 64;
  const int z    = blockIdx.y;

  const float* X       = z ? x2 : x1;
  unsigned short* outp = z ? o2 : o1;
  float* qp            = z ? qp2 : qp1;

  f32x4 accF[4][4], accM[4][4];
#pragma unroll
  for (int m = 0; m < 4; ++m)
#pragma unroll
    for (int n = 0; n < 4; ++n) { accF[m][n] = (f32x4){0,0,0,0}; accM[m][n] = (f32x4){0,0,0,0}; }

  // A staging geometry (fp32 -> bf16 via registers)
  const int ar = tid >> 2;           // 0..63 row in tile
  const int ako = (tid & 3) * 8;     // k element offset (8 elems = 16B bf16 = 32B fp32)
  // B staging geometry (global_load_lds, wave-linear)
  const int lrow = lane >> 2;
  const int lkk  = (lane & 3) * 8;

#define STAGE_B(buf, k0) do { \
  _Pragma("unroll") \
  for (int c = 0; c < 4; ++c) { \
    const int chunk = wave * 4 + c; \
    const int rb = (chunk*16 + lrow)*DD + (k0) + lkk; \
    gload_lds16(B1 + rb, &B1s[buf][chunk*512]); \
    gload_lds16(B2 + rb, &B2s[buf][chunk*512]); \
  } } while (0)

#define LOAD_A(k0) \
  float4 a0 = *(const float4*)(X + (long long)(row0 + ar)*DD + (k0) + ako); \
  float4 a1 = *(const float4*)(X + (long long)(row0 + ar)*DD + (k0) + ako + 4)

#define CVT_WRITE_A(buf) do { \
  union { unsigned short us[8]; int4 v; } u; \
  u.us[0]=f2bf(a0.x); u.us[1]=f2bf(a0.y); u.us[2]=f2bf(a0.z); u.us[3]=f2bf(a0.w); \
  u.us[4]=f2bf(a1.x); u.us[5]=f2bf(a1.y); u.us[6]=f2bf(a1.z); u.us[7]=f2bf(a1.w); \
  *(int4*)&As[buf][ar*32 + ako] = u.v; } while (0)

  // prologue: stage k-step 0
  {
    LOAD_A(0);
    STAGE_B(0, 0);
    CVT_WRITE_A(0);
  }
  __syncthreads();

  const int lr = lane & 15;
  const int lk = (lane >> 4) * 8;

#pragma unroll
  for (int kt = 0; kt < 8; ++kt) {
    const int cur = kt & 1;
    if (kt < 7) {
      const int k0 = (kt + 1) * 32;
      LOAD_A(k0);                 // issue early: latency hides under MFMA
      STAGE_B(cur ^ 1, k0);
      short8 af[4];
#pragma unroll
      for (int m = 0; m < 4; ++m) af[m] = *(const short8*)&As[cur][(m*16 + lr)*32 + lk];
#pragma unroll
      for (int n = 0; n < 4; ++n) {
        const short8 b1 = *(const short8*)&B1s[cur][(wave*64 + n*16 + lr)*32 + lk];
        const short8 b2 = *(const short8*)&B2s[cur][(wave*64 + n*16 + lr)*32 + lk];
#pragma unroll
        for (int m = 0; m < 4; ++m) {
          accF[m][n] = __builtin_amdgcn_mfma_f32_16x16x32_bf16(af[m], b1, accF[m][n], 0, 0, 0);
          accM[m][n] = __builtin_amdgcn_mfma_f32_16x16x32_bf16(af[m], b2, accM[m][n], 0, 0, 0);
        }
      }
      CVT_WRITE_A(cur ^ 1);       // after MFMA: vmcnt wait lands here, not before
    } else {
      short8 af[4];
#pragma unroll
      for (int m = 0; m < 4; ++m) af[m] = *(const short8*)&As[cur][(m*16 + lr)*32 + lk];
#pragma unroll
      for (int n = 0; n < 4; ++n) {
        const short8 b1 = *(const short8*)&B1s[cur][(wave*64 + n*16 + lr)*32 + lk];
        const short8 b2 = *(const short8*)&B2s[cur][(wave*64 + n*16 + lr)*32 + lk];
#pragma unroll
        for (int m = 0; m < 4; ++m) {
          accF[m][n] = __builtin_amdgcn_mfma_f32_16x16x32_bf16(af[m], b1, accF[m][n], 0, 0, 0);
          accM[m][n] = __builtin_amdgcn_mfma_f32_16x16x32_bf16(af[m], b2, accM[m][n], 0, 0, 0);
        }
      }
    }
    __syncthreads();
  }

  // epilogue — C/D layout: col = lane&15, row = (lane>>4)*4 + reg
  float bbv[4], bpv4[4];
#pragma unroll
  for (int n = 0; n < 4; ++n) {
    const int coll = wave*64 + n*16 + (lane & 15);
    bbv[n]  = bb[coll];
    bpv4[n] = bpv[coll];
  }
#pragma unroll
  for (int m = 0; m < 4; ++m) {
#pragma unroll
    for (int r = 0; r < 4; ++r) {
      const int rowl = m*16 + (lane >> 4)*4 + r;
      float p = 0.f;
#pragma unroll
      for (int n = 0; n < 4; ++n) {
        const int coll = wave*64 + n*16 + (lane & 15);
        const float fv  = accF[m][n][r] + bbv[n];
        const float fMv = accM[m][n][r] + bpv4[n];
        p += fv * fMv;
        outp[(long long)(row0 + rowl)*DD + coll] = f2bf(z ? fv : fMv);
      }
      p += __shfl_xor(p, 1); p += __shfl_xor(p, 2);
      p += __shfl_xor(p, 4); p += __shfl_xor(p, 8);
      if ((lane & 15) == 0) qp[wave*TROWS + row0 + rowl] = p;
    }
  }
#undef STAGE_B
#undef LOAD_A
#undef CVT_WRITE_A
}

// ---------------- batched cross GEMM + fused similarity epilogue ----------
// 1D grid, z = bid&7 pins each batch to one XCD (bijective: 2048 % 8 == 0).
__global__ __launch_bounds__(256, 2)
void k_cross(const unsigned short* __restrict__ f1M, const unsigned short* __restrict__ f2,
             const float* __restrict__ qp1, const float* __restrict__ qp2,
             float* __restrict__ out)
{
  __shared__ __align__(16) unsigned short As[2][128*32];
  __shared__ __align__(16) unsigned short Bs[2][128*32];
  __shared__ float q1s[128];
  __shared__ float q2s[128];

  const int tid  = threadIdx.x;
  const int lane = tid & 63;
  const int wave = tid >> 6;
  const int wr = wave >> 1;
  const int wc = wave & 1;

  const int bid = blockIdx.x;
  const int z  = bid & 7;
  const int t  = bid >> 3;
  const int bx = t & 15;
  const int by = t >> 4;
  const int row0 = by * 128;
  const int col0 = bx * 128;

  const unsigned short* A = f1M + (long long)z * NROW * DD;
  const unsigned short* B = f2  + (long long)z * NROW * DD;

  if (tid < 128) {
    const int rg = z*NROW + row0 + tid;
    q1s[tid] = qp1[rg] + qp1[TROWS + rg] + qp1[2*TROWS + rg] + qp1[3*TROWS + rg];
  } else {
    const int cg = z*NROW + col0 + (tid - 128);
    q2s[tid-128] = qp2[cg] + qp2[TROWS + cg] + qp2[2*TROWS + cg] + qp2[3*TROWS + cg];
  }

  f32x4 acc[4][4];
#pragma unroll
  for (int m = 0; m < 4; ++m)
#pragma unroll
    for (int n = 0; n < 4; ++n) acc[m][n] = (f32x4){0,0,0,0};

  const int lrow = lane >> 2;
  const int lkk  = (lane & 3) * 8;

#define STAGE_C(buf, k0) do { \
  _Pragma("unroll") \
  for (int c = 0; c < 2; ++c) { \
    const int chunk = wave * 2 + c; \
    gload_lds16(A + (long long)(row0 + chunk*16 + lrow)*DD + (k0) + lkk, &As[buf][chunk*512]); \
    gload_lds16(B + (long long)(col0 + chunk*16 + lrow)*DD + (k0) + lkk, &Bs[buf][chunk*512]); \
  } } while (0)

  STAGE_C(0, 0);
  __syncthreads();

  const int lr = lane & 15;
  const int lk = (lane >> 4) * 8;

#pragma unroll
  for (int kt = 0; kt < 8; ++kt) {
    const int cur = kt & 1;
    if (kt < 7) STAGE_C(cur ^ 1, (kt + 1) * 32);
    short8 af[4];
#pragma unroll
    for (int m = 0; m < 4; ++m) af[m] = *(const short8*)&As[cur][(wr*64 + m*16 + lr)*32 + lk];
#pragma unroll
    for (int n = 0; n < 4; ++n) {
      const short8 bfr = *(const short8*)&Bs[cur][(wc*64 + n*16 + lr)*32 + lk];
#pragma unroll
      for (int m = 0; m < 4; ++m)
        acc[m][n] = __builtin_amdgcn_mfma_f32_16x16x32_bf16(af[m], bfr, acc[m][n], 0, 0, 0);
    }
    __syncthreads();
  }

  float* outz = out + (long long)z * NROW * NROW;
#pragma unroll
  for (int m = 0; m < 4; ++m) {
#pragma unroll
    for (int r = 0; r < 4; ++r) {
      const int rowl = wr*64 + m*16 + (lane >> 4)*4 + r;
#pragma unroll
      for (int n = 0; n < 4; ++n) {
        const int coll = wc*64 + n*16 + (lane & 15);
        const float dsq = q1s[rowl] + q2s[coll] - 2.0f * acc[m][n][r];
        const float sc = fminf(fmaxf(-dsq, -10.0f), 10.0f);
        outz[(long long)(row0 + rowl)*NROW + (col0 + coll)] = __expf(sc);
      }
    }
  }
#undef STAGE_C
}

extern "C" void kernel_launch(void* const* d_in, const int* in_sizes, int n_in,
                              void* d_out, int out_size, void* d_ws, size_t ws_size,
                              hipStream_t stream) {
  const float* x1     = (const float*)d_in[0];
  const float* x2     = (const float*)d_in[1];
  const float* W      = (const float*)d_in[2];
  const float* bv     = (const float*)d_in[3];
  const float* metric = (const float*)d_in[4];
  float* out = (float*)d_out;

  if (ws_size < 20000000) return;
  unsigned short* p   = (unsigned short*)d_ws;
  unsigned short* f1M = p; p += (size_t)TROWS*DD;   // 8.4 MB
  unsigned short* f2  = p; p += (size_t)TROWS*DD;   // 8.4 MB
  unsigned short* Wbf = p; p += DD*DD;
  unsigned short* WpT = p; p += DD*DD;
  float* fp  = (float*)p;
  float* qp1 = fp; fp += 4*TROWS;
  float* qp2 = fp; fp += 4*TROWS;
  float* bp  = fp; fp += 256;

  // 1) prep (Wbf, WpT, bp)
  k_prep<<<256, 256, 0, stream>>>(metric, W, bv, Wbf, WpT, bp);
  // 2) fused convert + dual-B GEMM: f1M, f2, q partials
  dim3 gf(256, 2);
  k_fgemm<<<gf, 256, 0, stream>>>(x1, x2, Wbf, WpT, bv, bp, f1M, f2, qp1, qp2);
  // 3) cross GEMM + similarity epilogue (XCD-pinned)
  k_cross<<<2048, 256, 0, stream>>>(f1M, f2, qp1, qp2, out);
}